// Round 13
// baseline (85.034 us; speedup 1.0000x reference)
//
#include <hip/hip_runtime.h>
#include <hip/hip_bf16.h>

// GraphLayer: B=8, K=128, D=128, TPE=64, PPE=64, HEADS=8, G=16
// d_out = [v_out (8*128*128 f32) | e_value (8*16384*128 f32)]
//
// Round 13 = round 12 + ONE change: k_edge preloads all e_f A-operand data
// (16 f4v) in the prologue, so the HBM latency is absorbed once before the
// K-loop instead of stalling each of phases 0-3 at the vmcnt-draining barrier.

typedef __attribute__((ext_vector_type(8)))  short bh8;   // 8 x bf16 (as short)
typedef __attribute__((ext_vector_type(16))) float f16v;  // MFMA 32x32 accum
typedef __attribute__((ext_vector_type(4)))  float f4v;

__device__ __forceinline__ unsigned short f2bf(float f) {
  unsigned u = __builtin_bit_cast(unsigned, f);
  u += 0x7fffu + ((u >> 16) & 1u);          // RNE
  return (unsigned short)(u >> 16);
}
__device__ __forceinline__ float silu_f(float x) {
  float e = __builtin_amdgcn_exp2f(x * -1.44269504088896f);   // e^-x
  return x * __builtin_amdgcn_rcpf(1.f + e);
}
__device__ __forceinline__ bh8 cvt8(f4v x, f4v y) {
  bh8 a;
  a[0] = (short)f2bf(x[0]); a[1] = (short)f2bf(x[1]);
  a[2] = (short)f2bf(x[2]); a[3] = (short)f2bf(x[3]);
  a[4] = (short)f2bf(y[0]); a[5] = (short)f2bf(y[1]);
  a[6] = (short)f2bf(y[2]); a[7] = (short)f2bf(y[3]);
  return a;
}
typedef const __attribute__((address_space(1))) unsigned int gq_t;
typedef __attribute__((address_space(3))) unsigned int lq_t;
__device__ __forceinline__ void gload_lds16(const void* g, void* l) {
  // dest is wave-uniform base; HW adds lane*16. src is per-lane.
  __builtin_amdgcn_global_load_lds((gq_t*)g, (lq_t*)l, 16, 0, 0);
}
// monotonic f32 <-> u32 mapping for atomicMax-based float max
__device__ __forceinline__ unsigned fkey(float x) {
  unsigned u = __builtin_bit_cast(unsigned, x);
  return u ^ (((unsigned)((int)u >> 31)) | 0x80000000u);
}
__device__ __forceinline__ float funkey(unsigned key) {
  unsigned u = (key & 0x80000000u) ? (key ^ 0x80000000u) : ~key;
  return __builtin_bit_cast(float, u);
}

// ---------- weight frag layout ----------
// frag idx = ((ni*ksteps + ks)*64 + lane)*8 + jj ; col n = ni*32+(l&31), k = ks*16+(l>>5)*8+jj
__device__ __forceinline__ void wfrag_work(const float* __restrict__ W,
                                           short* __restrict__ dst, int kdim,
                                           int blk, int nblk) {
  int ksteps = kdim >> 4;
  int total  = kdim * 128;
  for (int idx = blk * 256 + threadIdx.x; idx < total; idx += nblk * 256) {
    int jj = idx & 7;
    int l  = (idx >> 3) & 63;
    int rest = idx >> 9;
    int ks = rest % ksteps;
    int ni = rest / ksteps;
    int n  = ni * 32 + (l & 31);
    int kk = ks * 16 + ((l >> 5) << 3) + jj;
    dst[idx] = (short)f2bf(W[kk * 128 + n]);
  }
}

// ---------- k_front: prep (0-259) + poolU zero (516) + node MLPs (260-515) ----------
__global__ __launch_bounds__(256) void k_front(
    const float* __restrict__ W_epe, short* __restrict__ wf1,
    const float* __restrict__ W_ev1, short* __restrict__ wf2,
    const float* __restrict__ W_ev2, short* __restrict__ wf3,
    const float* __restrict__ tpe, const float* __restrict__ bepe,
    float* __restrict__ tc, unsigned* __restrict__ poolU,
    const float* __restrict__ vfeat, const float* __restrict__ ppe,
    const float* __restrict__ Wv, const float* __restrict__ bv,
    const float* __restrict__ Wq, const float* __restrict__ bq,
    const float* __restrict__ Wk, const float* __restrict__ bk,
    const float* __restrict__ Ws, const float* __restrict__ bs,
    const float* __restrict__ We, const float* __restrict__ be,
    unsigned short* __restrict__ vb16, float* __restrict__ q,
    float* __restrict__ kb, float* __restrict__ sa, float* __restrict__ evi) {
  const int blk = blockIdx.x;
  if (blk < 260) {
    if (blk < 64)       wfrag_work(W_epe, wf1, 128, blk, 64);
    else if (blk < 192) wfrag_work(W_ev1 + 128 * 128, wf2, 256, blk - 64, 128);
    else if (blk < 256) wfrag_work(W_ev2, wf3, 128, blk - 192, 64);
    else {
      int t = threadIdx.x;
      int b = (blk - 256) * 2 + (t >> 7);
      int n = t & 127;
      float a = bepe[n];
      for (int k2 = 0; k2 < 64; ++k2)
        a += tpe[b * 64 + k2] * W_epe[(128 + k2) * 128 + n];
      tc[b * 128 + n] = a;
    }
    return;
  }
  if (blk >= 516) {                       // zero poolU each call (re-used buffer)
    for (int j = threadIdx.x; j < 1024; j += 256) poolU[j] = 0u;
    return;
  }
  // ----- node: 4 rows/block, 256 threads (split work across wave-pairs)
  __shared__ float x[4][256];
  __shared__ float par[2][4][128];
  __shared__ float xv[4][128];
  const int r0 = (blk - 260) * 4;
  const int b  = r0 >> 7;
  const int t  = threadIdx.x;
  const int c  = t & 127;
  const int hf = t >> 7;               // wave-uniform (0 for waves 0-1, 1 for 2-3)
  #pragma unroll
  for (int rr = 0; rr < 4; ++rr) {
    int row = r0 + rr;
    x[rr][t] = (t < 128) ? vfeat[row * 128 + t]
             : (t < 192) ? ppe[row * 64 + (t - 128)]
                         : tpe[b * 64 + (t - 192)];
  }
  __syncthreads();
  // stage 1: v = silu(x@Wv + bv), K=256 split across hf
  {
    float a0 = 0.f, a1 = 0.f, a2 = 0.f, a3 = 0.f;
    const int k0 = hf * 128;
    for (int k4 = k0; k4 < k0 + 128; k4 += 4) {
      f4v x0 = *(const f4v*)&x[0][k4];
      f4v x1 = *(const f4v*)&x[1][k4];
      f4v x2 = *(const f4v*)&x[2][k4];
      f4v x3 = *(const f4v*)&x[3][k4];
      #pragma unroll
      for (int u = 0; u < 4; ++u) {
        float wv = Wv[(k4 + u) * 128 + c];
        a0 += x0[u] * wv; a1 += x1[u] * wv; a2 += x2[u] * wv; a3 += x3[u] * wv;
      }
    }
    par[hf][0][c] = a0; par[hf][1][c] = a1; par[hf][2][c] = a2; par[hf][3][c] = a3;
  }
  __syncthreads();
  if (hf == 0) {
    const float bvv = bv[c];
    #pragma unroll
    for (int rr = 0; rr < 4; ++rr) {
      float s = silu_f(par[0][rr][c] + par[1][rr][c] + bvv);
      vb16[(r0 + rr) * 128 + c] = f2bf(s);
      xv[rr][c] = s;
    }
  }
  __syncthreads();
  // stage 2: hf=0 -> q,k ; hf=1 -> self,evi   (K=128 each)
  const float* WA = hf ? Ws : Wq;
  const float* WB = hf ? We : Wk;
  const float  ba = hf ? bs[c] : bq[c];
  const float  bb = hf ? be[c] : bk[c];
  float aA[4] = {ba, ba, ba, ba}, aB[4] = {bb, bb, bb, bb};
  for (int k4 = 0; k4 < 128; k4 += 4) {
    f4v x0 = *(const f4v*)&xv[0][k4];
    f4v x1 = *(const f4v*)&xv[1][k4];
    f4v x2 = *(const f4v*)&xv[2][k4];
    f4v x3 = *(const f4v*)&xv[3][k4];
    #pragma unroll
    for (int u = 0; u < 4; ++u) {
      float wa = WA[(k4 + u) * 128 + c];
      float wb = WB[(k4 + u) * 128 + c];
      aA[0] += x0[u] * wa; aA[1] += x1[u] * wa; aA[2] += x2[u] * wa; aA[3] += x3[u] * wa;
      aB[0] += x0[u] * wb; aB[1] += x1[u] * wb; aB[2] += x2[u] * wb; aB[3] += x3[u] * wb;
    }
  }
  if (hf == 0) {
    #pragma unroll
    for (int rr = 0; rr < 4; ++rr) {
      q[(r0 + rr) * 128 + c]  = aA[rr];
      kb[(r0 + rr) * 128 + c] = aB[rr];
    }
  } else {
    #pragma unroll
    for (int rr = 0; rr < 4; ++rr) {
      sa[(r0 + rr) * 128 + c]  = silu_f(aA[rr]);
      evi[(r0 + rr) * 128 + c] = aB[rr];   // v_i@W_ev1[0:128] + b_ev1 (no silu)
    }
  }
}

// ---------- atten: 2 i's per 256-thread block (512 blocks) ----------
__global__ __launch_bounds__(256) void k_atten(
    const float* __restrict__ q, const float* __restrict__ kmat,
    float* __restrict__ atten) {
  __shared__ float qr[2][128];
  __shared__ float s[2][128][17];
  __shared__ float red[2][8][17];
  __shared__ float gmax[2][16];
  __shared__ float gsum[2][16];
  const int tid = threadIdx.x;
  const int hi  = tid >> 7;              // which i of the pair
  const int tt  = tid & 127;             // acts as j
  const int bi  = blockIdx.x * 2 + hi;   // same b for both halves (bi0 even)
  const int b   = bi >> 7;
  qr[hi][tt] = q[(size_t)bi * 128 + tt];
  __syncthreads();
  const float sc = 0.20412414523193154f; // 1/sqrt(24)
  float loc[16];
  const float* krow = kmat + (size_t)(b * 128 + tt) * 128;
  #pragma unroll
  for (int g = 0; g < 16; ++g) {
    f4v k0 = *(const f4v*)&krow[g * 8];
    f4v k1 = *(const f4v*)&krow[g * 8 + 4];
    float a = 0.f;
    #pragma unroll
    for (int h = 0; h < 4; ++h)
      a += qr[hi][g * 8 + h] * k0[h] + qr[hi][g * 8 + 4 + h] * k1[h];
    loc[g] = a * sc;
    s[hi][tt][g] = loc[g];
  }
  __syncthreads();
  { int g = tt & 15, c = tt >> 4;
    float m = -1e30f;
    for (int j2 = c * 16; j2 < c * 16 + 16; ++j2) m = fmaxf(m, s[hi][j2][g]);
    red[hi][c][g] = m; }
  __syncthreads();
  if (tt < 16) {
    float m = red[hi][0][tt];
    #pragma unroll
    for (int c = 1; c < 8; ++c) m = fmaxf(m, red[hi][c][tt]);
    gmax[hi][tt] = m;
  }
  __syncthreads();
  #pragma unroll
  for (int g = 0; g < 16; ++g) {
    loc[g] = __builtin_amdgcn_exp2f((loc[g] - gmax[hi][g]) * 1.44269504088896f);
    s[hi][tt][g] = loc[g];
  }
  __syncthreads();
  { int g = tt & 15, c = tt >> 4;
    float m = 0.f;
    for (int j2 = c * 16; j2 < c * 16 + 16; ++j2) m += s[hi][j2][g];
    red[hi][c][g] = m; }
  __syncthreads();
  if (tt < 16) {
    float m = 0.f;
    #pragma unroll
    for (int c = 0; c < 8; ++c) m += red[hi][c][tt];
    gsum[hi][tt] = m;
  }
  __syncthreads();
  float* ab = atten + (size_t)bi * 2048 + (size_t)tt * 16;
  #pragma unroll
  for (int g = 0; g < 16; ++g) ab[g] = loc[g] * __builtin_amdgcn_rcpf(gsum[hi][g]);
}

// ---------- fused edge chain + in-block aggregation (round-7 loop, XCD swizzle,
//            e_f A-operands preloaded to registers) ----------
__global__ __launch_bounds__(256) void k_edge(
    const float* __restrict__ ef, const unsigned short* __restrict__ vb,
    const short* __restrict__ wf1, const short* __restrict__ wf2,
    const short* __restrict__ wf3, const float* __restrict__ tc,
    const float* __restrict__ evic, const float* __restrict__ bev2,
    const float* __restrict__ atten, const float* __restrict__ sab,
    float* __restrict__ oute, float* __restrict__ vfb,
    unsigned* __restrict__ poolU) {
  __shared__ __align__(16) unsigned short wbuf0[4096];      // 8KB chunk buffer
  __shared__ __align__(16) unsigned short wbuf1[4096];      // 8KB chunk buffer
  __shared__ __align__(16) unsigned short hbuf[128 * 136];  // 34816B, 272B stride
  // XCD-aware bijective swizzle (1024 % 8 == 0): XCD x gets bi in [x*128,(x+1)*128)
  const int bi  = ((blockIdx.x & 7) << 7) | (blockIdx.x >> 3);
  const int b   = bi >> 7;
  const int tid = threadIdx.x;
  const int w   = tid >> 6;
  const int l   = tid & 63;
  const int row = w * 32 + (l & 31);          // j index (A rows)
  const int kh  = (l >> 5) << 3;              // 0 or 8
  const int cb  = l & 31;                     // C/D col base
  const int rb  = w * 32 + ((l >> 5) << 2);   // C/D row base

  const float* efr = ef + (size_t)(bi * 128 + row) * 128;
  const unsigned short* vj = vb + (size_t)(b * 128 + row) * 128;

  auto stage2 = [&](const short* wfp, int KST, int kc, unsigned short* dstb) {
    #pragma unroll
    for (int it = 0; it < 2; ++it) {
      int g  = it * 4 + w;            // slot g: ni=g&3(=w), kso=g>>2(=it)
      int ni = g & 3, kso = g >> 2;
      const short* src = wfp + ((size_t)(ni * KST + kc * 2 + kso) * 64 + l) * 8;
      gload_lds16(src, dstb + g * 512);
    }
  };
  f16v acc[4];
  auto compute2 = [&](const unsigned short* ws2, bh8 aa, bh8 ab2) {
    #pragma unroll
    for (int ni = 0; ni < 4; ++ni) {
      bh8 b0 = *(const bh8*)&ws2[ni * 512 + l * 8];
      acc[ni] = __builtin_amdgcn_mfma_f32_32x32x16_bf16(aa, b0, acc[ni], 0, 0, 0);
    }
    #pragma unroll
    for (int ni = 0; ni < 4; ++ni) {
      bh8 b1 = *(const bh8*)&ws2[(4 + ni) * 512 + l * 8];
      acc[ni] = __builtin_amdgcn_mfma_f32_32x32x16_bf16(ab2, b1, acc[ni], 0, 0, 0);
    }
  };

  // ===== prologue: issue stage(0), then ALL e_f loads (one HBM latency, here)
  stage2(wf1, 8, 0, wbuf0);
  f4v efraw[16];
  #pragma unroll
  for (int u = 0; u < 8; ++u) {
    efraw[2 * u]     = *(const f4v*)(efr + u * 16 + kh);
    efraw[2 * u + 1] = *(const f4v*)(efr + u * 16 + kh + 4);
  }

  // A-operand for global kstep t: 0-7 e_f(regs), 8-15 v_j, 16-23 h1, 24-31 h2
  auto ldA = [&](int t) -> bh8 {
    if (t < 8) {
      return cvt8(efraw[2 * t], efraw[2 * t + 1]);
    } else if (t < 16) {
      return *(const bh8*)(vj + (t - 8) * 16 + kh);
    } else if (t < 24) {
      return *(const bh8*)&hbuf[row * 136 + (t - 16) * 16 + kh];
    } else {
      return *(const bh8*)&hbuf[row * 136 + (t - 24) * 16 + kh];
    }
  };

  float tin[4], ein[4];
  #pragma unroll
  for (int ni = 0; ni < 4; ++ni) {
    tin[ni] = tc[b * 128 + ni * 32 + cb];
    ein[ni] = evic[bi * 128 + ni * 32 + cb];
  }
  #pragma unroll
  for (int ni = 0; ni < 4; ++ni)
    #pragma unroll
    for (int r = 0; r < 16; ++r) acc[ni][r] = tin[ni];

  bh8 a0c = ldA(0), a1c = ldA(1);
  __syncthreads();

  #pragma unroll
  for (int c = 0; c < 16; ++c) {
    if (c + 1 < 16) {
      const short* wp; int KST, kc;
      if (c + 1 < 4)       { wp = wf1; KST = 8;  kc = c + 1; }
      else if (c + 1 < 12) { wp = wf2; KST = 16; kc = c + 1 - 4; }
      else                 { wp = wf3; KST = 8;  kc = c + 1 - 12; }
      stage2(wp, KST, kc, (c & 1) ? wbuf0 : wbuf1);
    }
    bh8 a0n, a1n;
    const bool pre = (c + 1 < 16) && (c != 11);   // c=11->12 crosses h2 epi
    if (pre) { a0n = ldA(2 * (c + 1)); a1n = ldA(2 * (c + 1) + 1); }
    compute2((c & 1) ? wbuf1 : wbuf0, a0c, a1c);
    if (c == 3) {            // h1 -> hbuf (same-wave rows); acc := evic
      #pragma unroll
      for (int ni = 0; ni < 4; ++ni) {
        int n = ni * 32 + cb;
        #pragma unroll
        for (int r = 0; r < 16; ++r) {
          int rj = rb + (r & 3) + ((r >> 2) << 3);
          hbuf[rj * 136 + n] = f2bf(silu_f(acc[ni][r]));
          acc[ni][r] = ein[ni];
        }
      }
    }
    if (c == 11) {           // h2 -> hbuf; acc := 0; L3 A direct from hbuf
      #pragma unroll
      for (int ni = 0; ni < 4; ++ni) {
        int n = ni * 32 + cb;
        #pragma unroll
        for (int r = 0; r < 16; ++r) {
          int rj = rb + (r & 3) + ((r >> 2) << 3);
          hbuf[rj * 136 + n] = f2bf(silu_f(acc[ni][r]));
          acc[ni][r] = 0.f;
        }
      }
      a0c = ldA(24); a1c = ldA(25);
    } else if (pre) {
      a0c = a0n; a1c = a1n;
    }
    __syncthreads();
  }

  // ===== epilogue: bias + e_value store
  #pragma unroll
  for (int ni = 0; ni < 4; ++ni) {
    int n = ni * 32 + cb;
    float bv = bev2[n];
    #pragma unroll
    for (int r = 0; r < 16; ++r) {
      int rj = rb + (r & 3) + ((r >> 2) << 3);
      acc[ni][r] += bv;
      oute[(size_t)(bi * 128 + rj) * 128 + n] = acc[ni][r];
    }
  }

  // ===== in-block aggregation: vf[n] = sum_j atten[j][n>>3]*ev[j][n] + silu_self
  __syncthreads();                       // all h2 hbuf reads done before overwrite
  float* attf = (float*)hbuf;            // [j][gl][ni] transposed, 2048 f32
  float* aggl = attf + 2048;             // [4 waves][128]
  const float* ap = atten + (size_t)bi * 2048;
  #pragma unroll
  for (int u = 0; u < 8; ++u) {
    int idx = u * 256 + tid;
    float v = ap[idx];
    int j2 = idx >> 4, g = idx & 15;
    attf[j2 * 16 + (g & 3) * 4 + (g >> 2)] = v;
  }
  float sav = 0.f;
  if (tid < 128) sav = sab[(size_t)bi * 128 + tid];
  __syncthreads();
  float p0 = 0.f, p1 = 0.f, p2 = 0.f, p3 = 0.f;
  const int gl = (l & 31) >> 3;
  #pragma unroll
  for (int r = 0; r < 16; ++r) {
    int rj = rb + (r & 3) + ((r >> 2) << 3);
    f4v av = *(const f4v*)&attf[rj * 16 + gl * 4];
    p0 += av[0] * acc[0][r]; p1 += av[1] * acc[1][r];
    p2 += av[2] * acc[2][r]; p3 += av[3] * acc[3][r];
  }
  p0 += __shfl_xor(p0, 32); p1 += __shfl_xor(p1, 32);
  p2 += __shfl_xor(p2, 32); p3 += __shfl_xor(p3, 32);
  if (l < 32) {
    aggl[w * 128 +  0 + l] = p0;
    aggl[w * 128 + 32 + l] = p1;
    aggl[w * 128 + 64 + l] = p2;
    aggl[w * 128 + 96 + l] = p3;
  }
  __syncthreads();
  if (tid < 128) {
    float vf = aggl[tid] + aggl[128 + tid] + aggl[256 + tid] + aggl[384 + tid] + sav;
    vfb[(size_t)bi * 128 + tid] = vf;
    atomicMax(&poolU[b * 128 + tid], fkey(vf));   // device-scope, XCD-coherent
  }
}

// ---------- out MLP: v_out = silu([vf|pool] @ W_out + b), split-K ----------
__global__ __launch_bounds__(256) void k_out(
    const float* __restrict__ vfb, const unsigned* __restrict__ poolU,
    const float* __restrict__ W, const float* __restrict__ bias,
    float* __restrict__ vout) {
  __shared__ float x[4][256];
  __shared__ float par[2][4][128];
  const int r0 = blockIdx.x * 4;
  const int b  = r0 >> 7;
  const int t  = threadIdx.x;
  const int c  = t & 127;
  const int hf = t >> 7;
  #pragma unroll
  for (int rr = 0; rr < 4; ++rr)
    x[rr][t] = (t < 128) ? vfb[(r0 + rr) * 128 + t]
                         : funkey(poolU[b * 128 + (t - 128)]);
  __syncthreads();
  {
    float a0 = 0.f, a1 = 0.f, a2 = 0.f, a3 = 0.f;
    const int k0 = hf * 128;
    for (int k4 = k0; k4 < k0 + 128; k4 += 4) {
      f4v x0 = *(const f4v*)&x[0][k4];
      f4v x1 = *(const f4v*)&x[1][k4];
      f4v x2 = *(const f4v*)&x[2][k4];
      f4v x3 = *(const f4v*)&x[3][k4];
      #pragma unroll
      for (int u = 0; u < 4; ++u) {
        float wv = W[(k4 + u) * 128 + c];
        a0 += x0[u] * wv; a1 += x1[u] * wv; a2 += x2[u] * wv; a3 += x3[u] * wv;
      }
    }
    par[hf][0][c] = a0; par[hf][1][c] = a1; par[hf][2][c] = a2; par[hf][3][c] = a3;
  }
  __syncthreads();
  if (hf == 0) {
    const float bvv = bias[c];
    #pragma unroll
    for (int rr = 0; rr < 4; ++rr)
      vout[(r0 + rr) * 128 + c] = silu_f(par[0][rr][c] + par[1][rr][c] + bvv);
  }
}

extern "C" void kernel_launch(void* const* d_in, const int* in_sizes, int n_in,
                              void* d_out, int out_size, void* d_ws, size_t ws_size,
                              hipStream_t stream) {
  const float* v_f    = (const float*)d_in[0];
  const float* e_f    = (const float*)d_in[1];
  const float* p_pe   = (const float*)d_in[2];
  const float* t_pe   = (const float*)d_in[3];
  const float* W_vpe  = (const float*)d_in[4];
  const float* b_vpe  = (const float*)d_in[5];
  const float* W_epe  = (const float*)d_in[6];
  const float* b_epe  = (const float*)d_in[7];
  const float* W_ev1  = (const float*)d_in[8];
  const float* b_ev1  = (const float*)d_in[9];
  const float* W_ev2  = (const float*)d_in[10];
  const float* b_ev2  = (const float*)d_in[11];
  const float* W_q    = (const float*)d_in[12];
  const float* b_q    = (const float*)d_in[13];
  const float* W_k    = (const float*)d_in[14];
  const float* b_k    = (const float*)d_in[15];
  const float* W_self = (const float*)d_in[16];
  const float* b_self = (const float*)d_in[17];
  const float* W_out  = (const float*)d_in[18];
  const float* b_out  = (const float*)d_in[19];

  char* ws = (char*)d_ws;
  unsigned short* vb16  = (unsigned short*)(ws + 0);        // 262144
  float*          qbuf  = (float*)(ws + 262144);            // 524288
  float*          kbuf  = (float*)(ws + 786432);            // 524288
  float*          sabuf = (float*)(ws + 1310720);           // 524288
  float*          vfbuf = (float*)(ws + 1835008);           // 524288
  float*          evic  = (float*)(ws + 2359296);           // 524288
  unsigned*       poolU = (unsigned*)(ws + 2883584);        // 4096
  float*          tc    = (float*)(ws + 2887680);           // 4096
  short*          wf1   = (short*)(ws + 2891776);           // 32768
  short*          wf2   = (short*)(ws + 2924544);           // 65536
  short*          wf3   = (short*)(ws + 2990080);           // 32768
  float*          atten = (float*)(ws + 3022848);           // 8388608 -> 11.4MB

  float* v_out = (float*)d_out;
  float* out_e = (float*)d_out + 131072;

  k_front<<<517, 256, 0, stream>>>(W_epe, wf1, W_ev1, wf2, W_ev2, wf3,
                                   t_pe, b_epe, tc, poolU,
                                   v_f, p_pe, W_vpe, b_vpe, W_q, b_q,
                                   W_k, b_k, W_self, b_self, W_ev1, b_ev1,
                                   vb16, qbuf, kbuf, sabuf, evic);
  k_atten<<<512, 256, 0, stream>>>(qbuf, kbuf, atten);
  k_edge<<<1024, 256, 0, stream>>>(e_f, vb16, wf1, wf2, wf3, tc, evic,
                                   b_ev2, atten, sabuf, out_e, vfbuf, poolU);
  k_out<<<256, 256, 0, stream>>>(vfbuf, poolU, W_out, b_out, v_out);
}

// Round 14
// 77.896 us; speedup vs baseline: 1.0916x; 1.0916x over previous
//
#include <hip/hip_runtime.h>
#include <hip/hip_bf16.h>

// GraphLayer: B=8, K=128, D=128, TPE=64, PPE=64, HEADS=8, G=16
// d_out = [v_out (8*128*128 f32) | e_value (8*16384*128 f32)]
//
// Round 14 = round 12 (best, 81.7us) with tail occupancy fixes only:
// k_front node section and k_out use 2 rows/block (2 blocks/CU, 2 waves/SIMD)
// instead of 4 rows/block (1 block/CU). k_edge/k_atten untouched.

typedef __attribute__((ext_vector_type(8)))  short bh8;   // 8 x bf16 (as short)
typedef __attribute__((ext_vector_type(16))) float f16v;  // MFMA 32x32 accum
typedef __attribute__((ext_vector_type(4)))  float f4v;

__device__ __forceinline__ unsigned short f2bf(float f) {
  unsigned u = __builtin_bit_cast(unsigned, f);
  u += 0x7fffu + ((u >> 16) & 1u);          // RNE
  return (unsigned short)(u >> 16);
}
__device__ __forceinline__ float silu_f(float x) {
  float e = __builtin_amdgcn_exp2f(x * -1.44269504088896f);   // e^-x
  return x * __builtin_amdgcn_rcpf(1.f + e);
}
__device__ __forceinline__ bh8 cvt8(f4v x, f4v y) {
  bh8 a;
  a[0] = (short)f2bf(x[0]); a[1] = (short)f2bf(x[1]);
  a[2] = (short)f2bf(x[2]); a[3] = (short)f2bf(x[3]);
  a[4] = (short)f2bf(y[0]); a[5] = (short)f2bf(y[1]);
  a[6] = (short)f2bf(y[2]); a[7] = (short)f2bf(y[3]);
  return a;
}
typedef const __attribute__((address_space(1))) unsigned int gq_t;
typedef __attribute__((address_space(3))) unsigned int lq_t;
__device__ __forceinline__ void gload_lds16(const void* g, void* l) {
  // dest is wave-uniform base; HW adds lane*16. src is per-lane.
  __builtin_amdgcn_global_load_lds((gq_t*)g, (lq_t*)l, 16, 0, 0);
}
// monotonic f32 <-> u32 mapping for atomicMax-based float max
__device__ __forceinline__ unsigned fkey(float x) {
  unsigned u = __builtin_bit_cast(unsigned, x);
  return u ^ (((unsigned)((int)u >> 31)) | 0x80000000u);
}
__device__ __forceinline__ float funkey(unsigned key) {
  unsigned u = (key & 0x80000000u) ? (key ^ 0x80000000u) : ~key;
  return __builtin_bit_cast(float, u);
}

// ---------- weight frag layout ----------
// frag idx = ((ni*ksteps + ks)*64 + lane)*8 + jj ; col n = ni*32+(l&31), k = ks*16+(l>>5)*8+jj
__device__ __forceinline__ void wfrag_work(const float* __restrict__ W,
                                           short* __restrict__ dst, int kdim,
                                           int blk, int nblk) {
  int ksteps = kdim >> 4;
  int total  = kdim * 128;
  for (int idx = blk * 256 + threadIdx.x; idx < total; idx += nblk * 256) {
    int jj = idx & 7;
    int l  = (idx >> 3) & 63;
    int rest = idx >> 9;
    int ks = rest % ksteps;
    int ni = rest / ksteps;
    int n  = ni * 32 + (l & 31);
    int kk = ks * 16 + ((l >> 5) << 3) + jj;
    dst[idx] = (short)f2bf(W[kk * 128 + n]);
  }
}

// ---------- k_front: prep (0-259) + poolU zero (260) + node MLPs (261-772) ----------
__global__ __launch_bounds__(256) void k_front(
    const float* __restrict__ W_epe, short* __restrict__ wf1,
    const float* __restrict__ W_ev1, short* __restrict__ wf2,
    const float* __restrict__ W_ev2, short* __restrict__ wf3,
    const float* __restrict__ tpe, const float* __restrict__ bepe,
    float* __restrict__ tc, unsigned* __restrict__ poolU,
    const float* __restrict__ vfeat, const float* __restrict__ ppe,
    const float* __restrict__ Wv, const float* __restrict__ bv,
    const float* __restrict__ Wq, const float* __restrict__ bq,
    const float* __restrict__ Wk, const float* __restrict__ bk,
    const float* __restrict__ Ws, const float* __restrict__ bs,
    const float* __restrict__ We, const float* __restrict__ be,
    unsigned short* __restrict__ vb16, float* __restrict__ q,
    float* __restrict__ kb, float* __restrict__ sa, float* __restrict__ evi) {
  const int blk = blockIdx.x;
  if (blk < 260) {
    if (blk < 64)       wfrag_work(W_epe, wf1, 128, blk, 64);
    else if (blk < 192) wfrag_work(W_ev1 + 128 * 128, wf2, 256, blk - 64, 128);
    else if (blk < 256) wfrag_work(W_ev2, wf3, 128, blk - 192, 64);
    else {
      int t = threadIdx.x;
      int b = (blk - 256) * 2 + (t >> 7);
      int n = t & 127;
      float a = bepe[n];
      for (int k2 = 0; k2 < 64; ++k2)
        a += tpe[b * 64 + k2] * W_epe[(128 + k2) * 128 + n];
      tc[b * 128 + n] = a;
    }
    return;
  }
  if (blk == 260) {                       // zero poolU each call (re-used buffer)
    for (int j = threadIdx.x; j < 1024; j += 256) poolU[j] = 0u;
    return;
  }
  // ----- node: 2 rows/block, 256 threads (split work across wave-pairs)
  __shared__ float x[2][256];
  __shared__ float par[2][2][128];
  __shared__ float xv[2][128];
  const int r0 = (blk - 261) * 2;
  const int b  = r0 >> 7;
  const int t  = threadIdx.x;
  const int c  = t & 127;
  const int hf = t >> 7;               // wave-uniform (0 for waves 0-1, 1 for 2-3)
  #pragma unroll
  for (int rr = 0; rr < 2; ++rr) {
    int row = r0 + rr;
    x[rr][t] = (t < 128) ? vfeat[row * 128 + t]
             : (t < 192) ? ppe[row * 64 + (t - 128)]
                         : tpe[b * 64 + (t - 192)];
  }
  __syncthreads();
  // stage 1: v = silu(x@Wv + bv), K=256 split across hf
  {
    float a0 = 0.f, a1 = 0.f;
    const int k0 = hf * 128;
    for (int k4 = k0; k4 < k0 + 128; k4 += 4) {
      f4v x0 = *(const f4v*)&x[0][k4];
      f4v x1 = *(const f4v*)&x[1][k4];
      #pragma unroll
      for (int u = 0; u < 4; ++u) {
        float wv = Wv[(k4 + u) * 128 + c];
        a0 += x0[u] * wv; a1 += x1[u] * wv;
      }
    }
    par[hf][0][c] = a0; par[hf][1][c] = a1;
  }
  __syncthreads();
  if (hf == 0) {
    const float bvv = bv[c];
    #pragma unroll
    for (int rr = 0; rr < 2; ++rr) {
      float s = silu_f(par[0][rr][c] + par[1][rr][c] + bvv);
      vb16[(r0 + rr) * 128 + c] = f2bf(s);
      xv[rr][c] = s;
    }
  }
  __syncthreads();
  // stage 2: hf=0 -> q,k ; hf=1 -> self,evi   (K=128 each)
  const float* WA = hf ? Ws : Wq;
  const float* WB = hf ? We : Wk;
  const float  ba = hf ? bs[c] : bq[c];
  const float  bb = hf ? be[c] : bk[c];
  float aA[2] = {ba, ba}, aB[2] = {bb, bb};
  for (int k4 = 0; k4 < 128; k4 += 4) {
    f4v x0 = *(const f4v*)&xv[0][k4];
    f4v x1 = *(const f4v*)&xv[1][k4];
    #pragma unroll
    for (int u = 0; u < 4; ++u) {
      float wa = WA[(k4 + u) * 128 + c];
      float wb = WB[(k4 + u) * 128 + c];
      aA[0] += x0[u] * wa; aA[1] += x1[u] * wa;
      aB[0] += x0[u] * wb; aB[1] += x1[u] * wb;
    }
  }
  if (hf == 0) {
    #pragma unroll
    for (int rr = 0; rr < 2; ++rr) {
      q[(r0 + rr) * 128 + c]  = aA[rr];
      kb[(r0 + rr) * 128 + c] = aB[rr];
    }
  } else {
    #pragma unroll
    for (int rr = 0; rr < 2; ++rr) {
      sa[(r0 + rr) * 128 + c]  = silu_f(aA[rr]);
      evi[(r0 + rr) * 128 + c] = aB[rr];   // v_i@W_ev1[0:128] + b_ev1 (no silu)
    }
  }
}

// ---------- atten: 2 i's per 256-thread block (512 blocks) ----------
__global__ __launch_bounds__(256) void k_atten(
    const float* __restrict__ q, const float* __restrict__ kmat,
    float* __restrict__ atten) {
  __shared__ float qr[2][128];
  __shared__ float s[2][128][17];
  __shared__ float red[2][8][17];
  __shared__ float gmax[2][16];
  __shared__ float gsum[2][16];
  const int tid = threadIdx.x;
  const int hi  = tid >> 7;              // which i of the pair
  const int tt  = tid & 127;             // acts as j
  const int bi  = blockIdx.x * 2 + hi;   // same b for both halves (bi0 even)
  const int b   = bi >> 7;
  qr[hi][tt] = q[(size_t)bi * 128 + tt];
  __syncthreads();
  const float sc = 0.20412414523193154f; // 1/sqrt(24)
  float loc[16];
  const float* krow = kmat + (size_t)(b * 128 + tt) * 128;
  #pragma unroll
  for (int g = 0; g < 16; ++g) {
    f4v k0 = *(const f4v*)&krow[g * 8];
    f4v k1 = *(const f4v*)&krow[g * 8 + 4];
    float a = 0.f;
    #pragma unroll
    for (int h = 0; h < 4; ++h)
      a += qr[hi][g * 8 + h] * k0[h] + qr[hi][g * 8 + 4 + h] * k1[h];
    loc[g] = a * sc;
    s[hi][tt][g] = loc[g];
  }
  __syncthreads();
  { int g = tt & 15, c = tt >> 4;
    float m = -1e30f;
    for (int j2 = c * 16; j2 < c * 16 + 16; ++j2) m = fmaxf(m, s[hi][j2][g]);
    red[hi][c][g] = m; }
  __syncthreads();
  if (tt < 16) {
    float m = red[hi][0][tt];
    #pragma unroll
    for (int c = 1; c < 8; ++c) m = fmaxf(m, red[hi][c][tt]);
    gmax[hi][tt] = m;
  }
  __syncthreads();
  #pragma unroll
  for (int g = 0; g < 16; ++g) {
    loc[g] = __builtin_amdgcn_exp2f((loc[g] - gmax[hi][g]) * 1.44269504088896f);
    s[hi][tt][g] = loc[g];
  }
  __syncthreads();
  { int g = tt & 15, c = tt >> 4;
    float m = 0.f;
    for (int j2 = c * 16; j2 < c * 16 + 16; ++j2) m += s[hi][j2][g];
    red[hi][c][g] = m; }
  __syncthreads();
  if (tt < 16) {
    float m = 0.f;
    #pragma unroll
    for (int c = 0; c < 8; ++c) m += red[hi][c][tt];
    gsum[hi][tt] = m;
  }
  __syncthreads();
  float* ab = atten + (size_t)bi * 2048 + (size_t)tt * 16;
  #pragma unroll
  for (int g = 0; g < 16; ++g) ab[g] = loc[g] * __builtin_amdgcn_rcpf(gsum[hi][g]);
}

// ---------- fused edge chain + in-block aggregation (round-7 loop, XCD swizzle) ----------
__global__ __launch_bounds__(256) void k_edge(
    const float* __restrict__ ef, const unsigned short* __restrict__ vb,
    const short* __restrict__ wf1, const short* __restrict__ wf2,
    const short* __restrict__ wf3, const float* __restrict__ tc,
    const float* __restrict__ evic, const float* __restrict__ bev2,
    const float* __restrict__ atten, const float* __restrict__ sab,
    float* __restrict__ oute, float* __restrict__ vfb,
    unsigned* __restrict__ poolU) {
  __shared__ __align__(16) unsigned short wbuf0[4096];      // 8KB chunk buffer
  __shared__ __align__(16) unsigned short wbuf1[4096];      // 8KB chunk buffer
  __shared__ __align__(16) unsigned short hbuf[128 * 136];  // 34816B, 272B stride
  // XCD-aware bijective swizzle (1024 % 8 == 0): XCD x gets bi in [x*128,(x+1)*128)
  const int bi  = ((blockIdx.x & 7) << 7) | (blockIdx.x >> 3);
  const int b   = bi >> 7;
  const int tid = threadIdx.x;
  const int w   = tid >> 6;
  const int l   = tid & 63;
  const int row = w * 32 + (l & 31);          // j index (A rows)
  const int kh  = (l >> 5) << 3;              // 0 or 8
  const int cb  = l & 31;                     // C/D col base
  const int rb  = w * 32 + ((l >> 5) << 2);   // C/D row base

  const float* efr = ef + (size_t)(bi * 128 + row) * 128;
  const unsigned short* vj = vb + (size_t)(b * 128 + row) * 128;

  auto stage2 = [&](const short* wfp, int KST, int kc, unsigned short* dstb) {
    #pragma unroll
    for (int it = 0; it < 2; ++it) {
      int g  = it * 4 + w;            // slot g: ni=g&3(=w), kso=g>>2(=it)
      int ni = g & 3, kso = g >> 2;
      const short* src = wfp + ((size_t)(ni * KST + kc * 2 + kso) * 64 + l) * 8;
      gload_lds16(src, dstb + g * 512);
    }
  };
  f16v acc[4];
  auto compute2 = [&](const unsigned short* ws2, bh8 aa, bh8 ab2) {
    #pragma unroll
    for (int ni = 0; ni < 4; ++ni) {
      bh8 b0 = *(const bh8*)&ws2[ni * 512 + l * 8];
      acc[ni] = __builtin_amdgcn_mfma_f32_32x32x16_bf16(aa, b0, acc[ni], 0, 0, 0);
    }
    #pragma unroll
    for (int ni = 0; ni < 4; ++ni) {
      bh8 b1 = *(const bh8*)&ws2[(4 + ni) * 512 + l * 8];
      acc[ni] = __builtin_amdgcn_mfma_f32_32x32x16_bf16(ab2, b1, acc[ni], 0, 0, 0);
    }
  };
  auto ldA = [&](int t) -> bh8 {
    if (t < 8) {
      const float* p = efr + t * 16 + kh;
      f4v x0 = *(const f4v*)p;
      f4v x1 = *(const f4v*)(p + 4);
      return cvt8(x0, x1);
    } else if (t < 16) {
      return *(const bh8*)(vj + (t - 8) * 16 + kh);
    } else if (t < 24) {
      return *(const bh8*)&hbuf[row * 136 + (t - 16) * 16 + kh];
    } else {
      return *(const bh8*)&hbuf[row * 136 + (t - 24) * 16 + kh];
    }
  };

  float tin[4], ein[4];
  #pragma unroll
  for (int ni = 0; ni < 4; ++ni) {
    tin[ni] = tc[b * 128 + ni * 32 + cb];
    ein[ni] = evic[bi * 128 + ni * 32 + cb];
  }
  #pragma unroll
  for (int ni = 0; ni < 4; ++ni)
    #pragma unroll
    for (int r = 0; r < 16; ++r) acc[ni][r] = tin[ni];

  stage2(wf1, 8, 0, wbuf0);
  bh8 a0c = ldA(0), a1c = ldA(1);
  __syncthreads();

  #pragma unroll
  for (int c = 0; c < 16; ++c) {
    if (c + 1 < 16) {
      const short* wp; int KST, kc;
      if (c + 1 < 4)       { wp = wf1; KST = 8;  kc = c + 1; }
      else if (c + 1 < 12) { wp = wf2; KST = 16; kc = c + 1 - 4; }
      else                 { wp = wf3; KST = 8;  kc = c + 1 - 12; }
      stage2(wp, KST, kc, (c & 1) ? wbuf0 : wbuf1);
    }
    bh8 a0n, a1n;
    const bool pre = (c + 1 < 16) && (c != 11);   // c=11->12 crosses h2 epi
    if (pre) { a0n = ldA(2 * (c + 1)); a1n = ldA(2 * (c + 1) + 1); }
    compute2((c & 1) ? wbuf1 : wbuf0, a0c, a1c);
    if (c == 3) {            // h1 -> hbuf (same-wave rows); acc := evic
      #pragma unroll
      for (int ni = 0; ni < 4; ++ni) {
        int n = ni * 32 + cb;
        #pragma unroll
        for (int r = 0; r < 16; ++r) {
          int rj = rb + (r & 3) + ((r >> 2) << 3);
          hbuf[rj * 136 + n] = f2bf(silu_f(acc[ni][r]));
          acc[ni][r] = ein[ni];
        }
      }
    }
    if (c == 11) {           // h2 -> hbuf; acc := 0; L3 A direct from hbuf
      #pragma unroll
      for (int ni = 0; ni < 4; ++ni) {
        int n = ni * 32 + cb;
        #pragma unroll
        for (int r = 0; r < 16; ++r) {
          int rj = rb + (r & 3) + ((r >> 2) << 3);
          hbuf[rj * 136 + n] = f2bf(silu_f(acc[ni][r]));
          acc[ni][r] = 0.f;
        }
      }
      a0c = ldA(24); a1c = ldA(25);
    } else if (pre) {
      a0c = a0n; a1c = a1n;
    }
    __syncthreads();
  }

  // ===== epilogue: bias + e_value store
  #pragma unroll
  for (int ni = 0; ni < 4; ++ni) {
    int n = ni * 32 + cb;
    float bv = bev2[n];
    #pragma unroll
    for (int r = 0; r < 16; ++r) {
      int rj = rb + (r & 3) + ((r >> 2) << 3);
      acc[ni][r] += bv;
      oute[(size_t)(bi * 128 + rj) * 128 + n] = acc[ni][r];
    }
  }

  // ===== in-block aggregation: vf[n] = sum_j atten[j][n>>3]*ev[j][n] + silu_self
  __syncthreads();                       // all h2 hbuf reads done before overwrite
  float* attf = (float*)hbuf;            // [j][gl][ni] transposed, 2048 f32
  float* aggl = attf + 2048;             // [4 waves][128]
  const float* ap = atten + (size_t)bi * 2048;
  #pragma unroll
  for (int u = 0; u < 8; ++u) {
    int idx = u * 256 + tid;
    float v = ap[idx];
    int j2 = idx >> 4, g = idx & 15;
    attf[j2 * 16 + (g & 3) * 4 + (g >> 2)] = v;
  }
  float sav = 0.f;
  if (tid < 128) sav = sab[(size_t)bi * 128 + tid];
  __syncthreads();
  float p0 = 0.f, p1 = 0.f, p2 = 0.f, p3 = 0.f;
  const int gl = (l & 31) >> 3;
  #pragma unroll
  for (int r = 0; r < 16; ++r) {
    int rj = rb + (r & 3) + ((r >> 2) << 3);
    f4v av = *(const f4v*)&attf[rj * 16 + gl * 4];
    p0 += av[0] * acc[0][r]; p1 += av[1] * acc[1][r];
    p2 += av[2] * acc[2][r]; p3 += av[3] * acc[3][r];
  }
  p0 += __shfl_xor(p0, 32); p1 += __shfl_xor(p1, 32);
  p2 += __shfl_xor(p2, 32); p3 += __shfl_xor(p3, 32);
  if (l < 32) {
    aggl[w * 128 +  0 + l] = p0;
    aggl[w * 128 + 32 + l] = p1;
    aggl[w * 128 + 64 + l] = p2;
    aggl[w * 128 + 96 + l] = p3;
  }
  __syncthreads();
  if (tid < 128) {
    float vf = aggl[tid] + aggl[128 + tid] + aggl[256 + tid] + aggl[384 + tid] + sav;
    vfb[(size_t)bi * 128 + tid] = vf;
    atomicMax(&poolU[b * 128 + tid], fkey(vf));   // device-scope, XCD-coherent
  }
}

// ---------- out MLP: v_out = silu([vf|pool] @ W_out + b), split-K, 2 rows ----------
__global__ __launch_bounds__(256) void k_out(
    const float* __restrict__ vfb, const unsigned* __restrict__ poolU,
    const float* __restrict__ W, const float* __restrict__ bias,
    float* __restrict__ vout) {
  __shared__ float x[2][256];
  __shared__ float par[2][2][128];
  const int r0 = blockIdx.x * 2;
  const int b  = r0 >> 7;
  const int t  = threadIdx.x;
  const int c  = t & 127;
  const int hf = t >> 7;
  #pragma unroll
  for (int rr = 0; rr < 2; ++rr)
    x[rr][t] = (t < 128) ? vfb[(r0 + rr) * 128 + t]
                         : funkey(poolU[b * 128 + (t - 128)]);
  __syncthreads();
  {
    float a0 = 0.f, a1 = 0.f;
    const int k0 = hf * 128;
    for (int k4 = k0; k4 < k0 + 128; k4 += 4) {
      f4v x0 = *(const f4v*)&x[0][k4];
      f4v x1 = *(const f4v*)&x[1][k4];
      #pragma unroll
      for (int u = 0; u < 4; ++u) {
        float wv = W[(k4 + u) * 128 + c];
        a0 += x0[u] * wv; a1 += x1[u] * wv;
      }
    }
    par[hf][0][c] = a0; par[hf][1][c] = a1;
  }
  __syncthreads();
  if (hf == 0) {
    const float bvv = bias[c];
    #pragma unroll
    for (int rr = 0; rr < 2; ++rr)
      vout[(r0 + rr) * 128 + c] = silu_f(par[0][rr][c] + par[1][rr][c] + bvv);
  }
}

extern "C" void kernel_launch(void* const* d_in, const int* in_sizes, int n_in,
                              void* d_out, int out_size, void* d_ws, size_t ws_size,
                              hipStream_t stream) {
  const float* v_f    = (const float*)d_in[0];
  const float* e_f    = (const float*)d_in[1];
  const float* p_pe   = (const float*)d_in[2];
  const float* t_pe   = (const float*)d_in[3];
  const float* W_vpe  = (const float*)d_in[4];
  const float* b_vpe  = (const float*)d_in[5];
  const float* W_epe  = (const float*)d_in[6];
  const float* b_epe  = (const float*)d_in[7];
  const float* W_ev1  = (const float*)d_in[8];
  const float* b_ev1  = (const float*)d_in[9];
  const float* W_ev2  = (const float*)d_in[10];
  const float* b_ev2  = (const float*)d_in[11];
  const float* W_q    = (const float*)d_in[12];
  const float* b_q    = (const float*)d_in[13];
  const float* W_k    = (const float*)d_in[14];
  const float* b_k    = (const float*)d_in[15];
  const float* W_self = (const float*)d_in[16];
  const float* b_self = (const float*)d_in[17];
  const float* W_out  = (const float*)d_in[18];
  const float* b_out  = (const float*)d_in[19];

  char* ws = (char*)d_ws;
  unsigned short* vb16  = (unsigned short*)(ws + 0);        // 262144
  float*          qbuf  = (float*)(ws + 262144);            // 524288
  float*          kbuf  = (float*)(ws + 786432);            // 524288
  float*          sabuf = (float*)(ws + 1310720);           // 524288
  float*          vfbuf = (float*)(ws + 1835008);           // 524288
  float*          evic  = (float*)(ws + 2359296);           // 524288
  unsigned*       poolU = (unsigned*)(ws + 2883584);        // 4096
  float*          tc    = (float*)(ws + 2887680);           // 4096
  short*          wf1   = (short*)(ws + 2891776);           // 32768
  short*          wf2   = (short*)(ws + 2924544);           // 65536
  short*          wf3   = (short*)(ws + 2990080);           // 32768
  float*          atten = (float*)(ws + 3022848);           // 8388608 -> 11.4MB

  float* v_out = (float*)d_out;
  float* out_e = (float*)d_out + 131072;

  k_front<<<773, 256, 0, stream>>>(W_epe, wf1, W_ev1, wf2, W_ev2, wf3,
                                   t_pe, b_epe, tc, poolU,
                                   v_f, p_pe, W_vpe, b_vpe, W_q, b_q,
                                   W_k, b_k, W_self, b_self, W_ev1, b_ev1,
                                   vb16, qbuf, kbuf, sabuf, evic);
  k_atten<<<512, 256, 0, stream>>>(qbuf, kbuf, atten);
  k_edge<<<1024, 256, 0, stream>>>(e_f, vb16, wf1, wf2, wf3, tc, evic,
                                   b_ev2, atten, sabuf, out_e, vfbuf, poolU);
  k_out<<<512, 256, 0, stream>>>(vfbuf, poolU, W_out, b_out, v_out);
}

// Round 15
// 76.320 us; speedup vs baseline: 1.1142x; 1.0206x over previous
//
#include <hip/hip_runtime.h>
#include <hip/hip_bf16.h>

// GraphLayer: B=8, K=128, D=128, TPE=64, PPE=64, HEADS=8, G=16
// d_out = [v_out (8*128*128 f32) | e_value (8*16384*128 f32)]
//
// Round 15 = round 14 (77.9us) + ONE k_edge change: wf1 (32KB) is staged into
// hbuf during the prologue (hbuf is dead until h1), so all 8 L1 ksteps run
// BARRIER-FREE from LDS-resident weights; e_f HBM latency is hidden by TLP
// across the 12 resident waves instead of serializing at per-phase barriers.

typedef __attribute__((ext_vector_type(8)))  short bh8;   // 8 x bf16 (as short)
typedef __attribute__((ext_vector_type(16))) float f16v;  // MFMA 32x32 accum
typedef __attribute__((ext_vector_type(4)))  float f4v;

__device__ __forceinline__ unsigned short f2bf(float f) {
  unsigned u = __builtin_bit_cast(unsigned, f);
  u += 0x7fffu + ((u >> 16) & 1u);          // RNE
  return (unsigned short)(u >> 16);
}
__device__ __forceinline__ float silu_f(float x) {
  float e = __builtin_amdgcn_exp2f(x * -1.44269504088896f);   // e^-x
  return x * __builtin_amdgcn_rcpf(1.f + e);
}
__device__ __forceinline__ bh8 cvt8(f4v x, f4v y) {
  bh8 a;
  a[0] = (short)f2bf(x[0]); a[1] = (short)f2bf(x[1]);
  a[2] = (short)f2bf(x[2]); a[3] = (short)f2bf(x[3]);
  a[4] = (short)f2bf(y[0]); a[5] = (short)f2bf(y[1]);
  a[6] = (short)f2bf(y[2]); a[7] = (short)f2bf(y[3]);
  return a;
}
typedef const __attribute__((address_space(1))) unsigned int gq_t;
typedef __attribute__((address_space(3))) unsigned int lq_t;
__device__ __forceinline__ void gload_lds16(const void* g, void* l) {
  // dest is wave-uniform base; HW adds lane*16. src is per-lane.
  __builtin_amdgcn_global_load_lds((gq_t*)g, (lq_t*)l, 16, 0, 0);
}
// monotonic f32 <-> u32 mapping for atomicMax-based float max
__device__ __forceinline__ unsigned fkey(float x) {
  unsigned u = __builtin_bit_cast(unsigned, x);
  return u ^ (((unsigned)((int)u >> 31)) | 0x80000000u);
}
__device__ __forceinline__ float funkey(unsigned key) {
  unsigned u = (key & 0x80000000u) ? (key ^ 0x80000000u) : ~key;
  return __builtin_bit_cast(float, u);
}

// ---------- weight frag layout ----------
// frag idx = ((ni*ksteps + ks)*64 + lane)*8 + jj ; col n = ni*32+(l&31), k = ks*16+(l>>5)*8+jj
__device__ __forceinline__ void wfrag_work(const float* __restrict__ W,
                                           short* __restrict__ dst, int kdim,
                                           int blk, int nblk) {
  int ksteps = kdim >> 4;
  int total  = kdim * 128;
  for (int idx = blk * 256 + threadIdx.x; idx < total; idx += nblk * 256) {
    int jj = idx & 7;
    int l  = (idx >> 3) & 63;
    int rest = idx >> 9;
    int ks = rest % ksteps;
    int ni = rest / ksteps;
    int n  = ni * 32 + (l & 31);
    int kk = ks * 16 + ((l >> 5) << 3) + jj;
    dst[idx] = (short)f2bf(W[kk * 128 + n]);
  }
}

// ---------- k_front: prep (0-259) + poolU zero (260) + node MLPs (261-772) ----------
__global__ __launch_bounds__(256) void k_front(
    const float* __restrict__ W_epe, short* __restrict__ wf1,
    const float* __restrict__ W_ev1, short* __restrict__ wf2,
    const float* __restrict__ W_ev2, short* __restrict__ wf3,
    const float* __restrict__ tpe, const float* __restrict__ bepe,
    float* __restrict__ tc, unsigned* __restrict__ poolU,
    const float* __restrict__ vfeat, const float* __restrict__ ppe,
    const float* __restrict__ Wv, const float* __restrict__ bv,
    const float* __restrict__ Wq, const float* __restrict__ bq,
    const float* __restrict__ Wk, const float* __restrict__ bk,
    const float* __restrict__ Ws, const float* __restrict__ bs,
    const float* __restrict__ We, const float* __restrict__ be,
    unsigned short* __restrict__ vb16, float* __restrict__ q,
    float* __restrict__ kb, float* __restrict__ sa, float* __restrict__ evi) {
  const int blk = blockIdx.x;
  if (blk < 260) {
    if (blk < 64)       wfrag_work(W_epe, wf1, 128, blk, 64);
    else if (blk < 192) wfrag_work(W_ev1 + 128 * 128, wf2, 256, blk - 64, 128);
    else if (blk < 256) wfrag_work(W_ev2, wf3, 128, blk - 192, 64);
    else {
      int t = threadIdx.x;
      int b = (blk - 256) * 2 + (t >> 7);
      int n = t & 127;
      float a = bepe[n];
      for (int k2 = 0; k2 < 64; ++k2)
        a += tpe[b * 64 + k2] * W_epe[(128 + k2) * 128 + n];
      tc[b * 128 + n] = a;
    }
    return;
  }
  if (blk == 260) {                       // zero poolU each call (re-used buffer)
    for (int j = threadIdx.x; j < 1024; j += 256) poolU[j] = 0u;
    return;
  }
  // ----- node: 2 rows/block, 256 threads (split work across wave-pairs)
  __shared__ float x[2][256];
  __shared__ float par[2][2][128];
  __shared__ float xv[2][128];
  const int r0 = (blk - 261) * 2;
  const int b  = r0 >> 7;
  const int t  = threadIdx.x;
  const int c  = t & 127;
  const int hf = t >> 7;               // wave-uniform (0 for waves 0-1, 1 for 2-3)
  #pragma unroll
  for (int rr = 0; rr < 2; ++rr) {
    int row = r0 + rr;
    x[rr][t] = (t < 128) ? vfeat[row * 128 + t]
             : (t < 192) ? ppe[row * 64 + (t - 128)]
                         : tpe[b * 64 + (t - 192)];
  }
  __syncthreads();
  // stage 1: v = silu(x@Wv + bv), K=256 split across hf
  {
    float a0 = 0.f, a1 = 0.f;
    const int k0 = hf * 128;
    for (int k4 = k0; k4 < k0 + 128; k4 += 4) {
      f4v x0 = *(const f4v*)&x[0][k4];
      f4v x1 = *(const f4v*)&x[1][k4];
      #pragma unroll
      for (int u = 0; u < 4; ++u) {
        float wv = Wv[(k4 + u) * 128 + c];
        a0 += x0[u] * wv; a1 += x1[u] * wv;
      }
    }
    par[hf][0][c] = a0; par[hf][1][c] = a1;
  }
  __syncthreads();
  if (hf == 0) {
    const float bvv = bv[c];
    #pragma unroll
    for (int rr = 0; rr < 2; ++rr) {
      float s = silu_f(par[0][rr][c] + par[1][rr][c] + bvv);
      vb16[(r0 + rr) * 128 + c] = f2bf(s);
      xv[rr][c] = s;
    }
  }
  __syncthreads();
  // stage 2: hf=0 -> q,k ; hf=1 -> self,evi   (K=128 each)
  const float* WA = hf ? Ws : Wq;
  const float* WB = hf ? We : Wk;
  const float  ba = hf ? bs[c] : bq[c];
  const float  bb = hf ? be[c] : bk[c];
  float aA[2] = {ba, ba}, aB[2] = {bb, bb};
  for (int k4 = 0; k4 < 128; k4 += 4) {
    f4v x0 = *(const f4v*)&xv[0][k4];
    f4v x1 = *(const f4v*)&xv[1][k4];
    #pragma unroll
    for (int u = 0; u < 4; ++u) {
      float wa = WA[(k4 + u) * 128 + c];
      float wb = WB[(k4 + u) * 128 + c];
      aA[0] += x0[u] * wa; aA[1] += x1[u] * wa;
      aB[0] += x0[u] * wb; aB[1] += x1[u] * wb;
    }
  }
  if (hf == 0) {
    #pragma unroll
    for (int rr = 0; rr < 2; ++rr) {
      q[(r0 + rr) * 128 + c]  = aA[rr];
      kb[(r0 + rr) * 128 + c] = aB[rr];
    }
  } else {
    #pragma unroll
    for (int rr = 0; rr < 2; ++rr) {
      sa[(r0 + rr) * 128 + c]  = silu_f(aA[rr]);
      evi[(r0 + rr) * 128 + c] = aB[rr];   // v_i@W_ev1[0:128] + b_ev1 (no silu)
    }
  }
}

// ---------- atten: 2 i's per 256-thread block (512 blocks) ----------
__global__ __launch_bounds__(256) void k_atten(
    const float* __restrict__ q, const float* __restrict__ kmat,
    float* __restrict__ atten) {
  __shared__ float qr[2][128];
  __shared__ float s[2][128][17];
  __shared__ float red[2][8][17];
  __shared__ float gmax[2][16];
  __shared__ float gsum[2][16];
  const int tid = threadIdx.x;
  const int hi  = tid >> 7;              // which i of the pair
  const int tt  = tid & 127;             // acts as j
  const int bi  = blockIdx.x * 2 + hi;   // same b for both halves (bi0 even)
  const int b   = bi >> 7;
  qr[hi][tt] = q[(size_t)bi * 128 + tt];
  __syncthreads();
  const float sc = 0.20412414523193154f; // 1/sqrt(24)
  float loc[16];
  const float* krow = kmat + (size_t)(b * 128 + tt) * 128;
  #pragma unroll
  for (int g = 0; g < 16; ++g) {
    f4v k0 = *(const f4v*)&krow[g * 8];
    f4v k1 = *(const f4v*)&krow[g * 8 + 4];
    float a = 0.f;
    #pragma unroll
    for (int h = 0; h < 4; ++h)
      a += qr[hi][g * 8 + h] * k0[h] + qr[hi][g * 8 + 4 + h] * k1[h];
    loc[g] = a * sc;
    s[hi][tt][g] = loc[g];
  }
  __syncthreads();
  { int g = tt & 15, c = tt >> 4;
    float m = -1e30f;
    for (int j2 = c * 16; j2 < c * 16 + 16; ++j2) m = fmaxf(m, s[hi][j2][g]);
    red[hi][c][g] = m; }
  __syncthreads();
  if (tt < 16) {
    float m = red[hi][0][tt];
    #pragma unroll
    for (int c = 1; c < 8; ++c) m = fmaxf(m, red[hi][c][tt]);
    gmax[hi][tt] = m;
  }
  __syncthreads();
  #pragma unroll
  for (int g = 0; g < 16; ++g) {
    loc[g] = __builtin_amdgcn_exp2f((loc[g] - gmax[hi][g]) * 1.44269504088896f);
    s[hi][tt][g] = loc[g];
  }
  __syncthreads();
  { int g = tt & 15, c = tt >> 4;
    float m = 0.f;
    for (int j2 = c * 16; j2 < c * 16 + 16; ++j2) m += s[hi][j2][g];
    red[hi][c][g] = m; }
  __syncthreads();
  if (tt < 16) {
    float m = 0.f;
    #pragma unroll
    for (int c = 0; c < 8; ++c) m += red[hi][c][tt];
    gsum[hi][tt] = m;
  }
  __syncthreads();
  float* ab = atten + (size_t)bi * 2048 + (size_t)tt * 16;
  #pragma unroll
  for (int g = 0; g < 16; ++g) ab[g] = loc[g] * __builtin_amdgcn_rcpf(gsum[hi][g]);
}

// ---------- fused edge chain + in-block aggregation ----------
// block=(b,i); 128 j; 4 waves x (32 rows x 128 cols); XCD swizzle.
// L1: wf1 LDS-resident in hbuf, 8 ksteps barrier-free (e_f latency TLP-hidden).
// L2: 8 chunks x 2 ksteps, wbuf dbuf (c0,c1 pre-staged in prologue).
// L3: 4 chunks (wf3 chunks 0,1 staged during L2 tail).
__global__ __launch_bounds__(256) void k_edge(
    const float* __restrict__ ef, const unsigned short* __restrict__ vb,
    const short* __restrict__ wf1, const short* __restrict__ wf2,
    const short* __restrict__ wf3, const float* __restrict__ tc,
    const float* __restrict__ evic, const float* __restrict__ bev2,
    const float* __restrict__ atten, const float* __restrict__ sab,
    float* __restrict__ oute, float* __restrict__ vfb,
    unsigned* __restrict__ poolU) {
  __shared__ __align__(16) unsigned short wbuf0[4096];      // 8KB chunk buffer
  __shared__ __align__(16) unsigned short wbuf1[4096];      // 8KB chunk buffer
  __shared__ __align__(16) unsigned short hbuf[128 * 136];  // wf1 slots, then h1/h2
  // XCD-aware bijective swizzle (1024 % 8 == 0)
  const int bi  = ((blockIdx.x & 7) << 7) | (blockIdx.x >> 3);
  const int b   = bi >> 7;
  const int tid = threadIdx.x;
  const int w   = tid >> 6;
  const int l   = tid & 63;
  const int row = w * 32 + (l & 31);          // j index (A rows)
  const int kh  = (l >> 5) << 3;              // 0 or 8
  const int cb  = l & 31;                     // C/D col base
  const int rb  = w * 32 + ((l >> 5) << 2);   // C/D row base

  const float* efr = ef + (size_t)(bi * 128 + row) * 128;
  const unsigned short* vj = vb + (size_t)(b * 128 + row) * 128;

  auto stage2 = [&](const short* wfp, int KST, int kc, unsigned short* dstb) {
    #pragma unroll
    for (int it = 0; it < 2; ++it) {
      int g  = it * 4 + w;            // slot g: ni=g&3(=w), kso=g>>2(=it)
      int ni = g & 3, kso = g >> 2;
      const short* src = wfp + ((size_t)(ni * KST + kc * 2 + kso) * 64 + l) * 8;
      gload_lds16(src, dstb + g * 512);
    }
  };
  f16v acc[4];
  auto compute2 = [&](const unsigned short* ws2, bh8 aa, bh8 ab2) {
    #pragma unroll
    for (int ni = 0; ni < 4; ++ni) {
      bh8 b0 = *(const bh8*)&ws2[ni * 512 + l * 8];
      acc[ni] = __builtin_amdgcn_mfma_f32_32x32x16_bf16(aa, b0, acc[ni], 0, 0, 0);
    }
    #pragma unroll
    for (int ni = 0; ni < 4; ++ni) {
      bh8 b1 = *(const bh8*)&ws2[(4 + ni) * 512 + l * 8];
      acc[ni] = __builtin_amdgcn_mfma_f32_32x32x16_bf16(ab2, b1, acc[ni], 0, 0, 0);
    }
  };
  auto ldAef = [&](int t) -> bh8 {    // e_f kstep t (0..7)
    const float* p = efr + t * 16 + kh;
    f4v x0 = *(const f4v*)p;
    f4v x1 = *(const f4v*)(p + 4);
    return cvt8(x0, x1);
  };

  // ===== prologue: wf1 -> hbuf (32 slots x 1KB), L2 chunks 0,1 -> wbufs
  #pragma unroll
  for (int it = 0; it < 8; ++it) {
    int s = it * 4 + w;
    gload_lds16(wf1 + ((size_t)s * 64 + l) * 8, hbuf + s * 512);
  }
  stage2(wf2, 16, 0, wbuf0);
  stage2(wf2, 16, 1, wbuf1);

  float tin[4], ein[4];
  #pragma unroll
  for (int ni = 0; ni < 4; ++ni) {
    tin[ni] = tc[b * 128 + ni * 32 + cb];
    ein[ni] = evic[bi * 128 + ni * 32 + cb];
  }
  #pragma unroll
  for (int ni = 0; ni < 4; ++ni)
    #pragma unroll
    for (int r = 0; r < 16; ++r) acc[ni][r] = tin[ni];

  bh8 a0c = ldAef(0), a1c = ldAef(1);
  __syncthreads();      // wf1 + c0 + c1 resident; one consolidated drain

  // ===== L1: ksteps 0..7 from hbuf-resident wf1; NO barriers (TLP hides e_f)
  #pragma unroll
  for (int p2 = 0; p2 < 4; ++p2) {
    bh8 a0n, a1n;
    if (p2 < 3) { a0n = ldAef(2 * p2 + 2); a1n = ldAef(2 * p2 + 3); }
    #pragma unroll
    for (int ni = 0; ni < 4; ++ni) {
      bh8 b0 = *(const bh8*)&hbuf[(ni * 8 + 2 * p2) * 512 + l * 8];
      acc[ni] = __builtin_amdgcn_mfma_f32_32x32x16_bf16(a0c, b0, acc[ni], 0, 0, 0);
    }
    #pragma unroll
    for (int ni = 0; ni < 4; ++ni) {
      bh8 b1 = *(const bh8*)&hbuf[(ni * 8 + 2 * p2 + 1) * 512 + l * 8];
      acc[ni] = __builtin_amdgcn_mfma_f32_32x32x16_bf16(a1c, b1, acc[ni], 0, 0, 0);
    }
    if (p2 < 3) { a0c = a0n; a1c = a1n; }
  }
  __syncthreads();      // all waves done reading wf1 slots (hbuf reuse next)

  // h1 -> hbuf rows (per-wave rows only); acc := evic
  #pragma unroll
  for (int ni = 0; ni < 4; ++ni) {
    int n = ni * 32 + cb;
    #pragma unroll
    for (int r = 0; r < 16; ++r) {
      int rj = rb + (r & 3) + ((r >> 2) << 3);
      hbuf[rj * 136 + n] = f2bf(silu_f(acc[ni][r]));
      acc[ni][r] = ein[ni];
    }
  }
  a0c = *(const bh8*)(vj + kh);            // kstep 8
  a1c = *(const bh8*)(vj + 16 + kh);       // kstep 9

  // ===== L2: chunks 0..7 = global ksteps 8..23 (8-15 v_j, 16-23 h1)
  #pragma unroll
  for (int c2 = 0; c2 < 8; ++c2) {
    bh8 a0n, a1n;
    if (c2 < 7) {
      const int t0 = 10 + 2 * c2, t1 = t0 + 1;
      a0n = (t0 < 16) ? *(const bh8*)(vj + (t0 - 8) * 16 + kh)
                      : *(const bh8*)&hbuf[row * 136 + (t0 - 16) * 16 + kh];
      a1n = (t1 < 16) ? *(const bh8*)(vj + (t1 - 8) * 16 + kh)
                      : *(const bh8*)&hbuf[row * 136 + (t1 - 16) * 16 + kh];
    }
    compute2((c2 & 1) ? wbuf1 : wbuf0, a0c, a1c);
    if (c2 < 7) { a0c = a0n; a1c = a1n; }
    __syncthreads();                       // chunk c2 consumed by all waves
    if (c2 + 2 < 8)       stage2(wf2, 16, c2 + 2, (c2 & 1) ? wbuf1 : wbuf0);
    else if (c2 + 2 < 12) stage2(wf3, 8, c2 + 2 - 8, (c2 & 1) ? wbuf1 : wbuf0);
  }

  // h2 -> hbuf rows (per-wave; own h1 reads complete in program order); acc := 0
  #pragma unroll
  for (int ni = 0; ni < 4; ++ni) {
    int n = ni * 32 + cb;
    #pragma unroll
    for (int r = 0; r < 16; ++r) {
      int rj = rb + (r & 3) + ((r >> 2) << 3);
      hbuf[rj * 136 + n] = f2bf(silu_f(acc[ni][r]));
      acc[ni][r] = 0.f;
    }
  }
  a0c = *(const bh8*)&hbuf[row * 136 + kh];        // kstep 24
  a1c = *(const bh8*)&hbuf[row * 136 + 16 + kh];   // kstep 25

  // ===== L3: chunks 0..3 (wf3; c0,c1 staged during L2 tail)
  #pragma unroll
  for (int c3 = 0; c3 < 4; ++c3) {
    bh8 a0n, a1n;
    if (c3 < 3) {
      a0n = *(const bh8*)&hbuf[row * 136 + (2 * c3 + 2) * 16 + kh];
      a1n = *(const bh8*)&hbuf[row * 136 + (2 * c3 + 3) * 16 + kh];
    }
    compute2((c3 & 1) ? wbuf1 : wbuf0, a0c, a1c);
    if (c3 < 3) { a0c = a0n; a1c = a1n; }
    __syncthreads();
    if (c3 + 2 < 4) stage2(wf3, 8, c3 + 2, (c3 & 1) ? wbuf1 : wbuf0);
  }

  // ===== epilogue: bias + e_value store
  #pragma unroll
  for (int ni = 0; ni < 4; ++ni) {
    int n = ni * 32 + cb;
    float bv = bev2[n];
    #pragma unroll
    for (int r = 0; r < 16; ++r) {
      int rj = rb + (r & 3) + ((r >> 2) << 3);
      acc[ni][r] += bv;
      oute[(size_t)(bi * 128 + rj) * 128 + n] = acc[ni][r];
    }
  }

  // ===== in-block aggregation: vf[n] = sum_j atten[j][n>>3]*ev[j][n] + silu_self
  __syncthreads();                       // hbuf reuse as arena
  float* attf = (float*)hbuf;            // [j][gl][ni] transposed, 2048 f32
  float* aggl = attf + 2048;             // [4 waves][128]
  const float* ap = atten + (size_t)bi * 2048;
  #pragma unroll
  for (int u = 0; u < 8; ++u) {
    int idx = u * 256 + tid;
    float v = ap[idx];
    int j2 = idx >> 4, g = idx & 15;
    attf[j2 * 16 + (g & 3) * 4 + (g >> 2)] = v;
  }
  float sav = 0.f;
  if (tid < 128) sav = sab[(size_t)bi * 128 + tid];
  __syncthreads();
  float p0 = 0.f, p1 = 0.f, p2 = 0.f, p3 = 0.f;
  const int gl = (l & 31) >> 3;
  #pragma unroll
  for (int r = 0; r < 16; ++r) {
    int rj = rb + (r & 3) + ((r >> 2) << 3);
    f4v av = *(const f4v*)&attf[rj * 16 + gl * 4];
    p0 += av[0] * acc[0][r]; p1 += av[1] * acc[1][r];
    p2 += av[2] * acc[2][r]; p3 += av[3] * acc[3][r];
  }
  p0 += __shfl_xor(p0, 32); p1 += __shfl_xor(p1, 32);
  p2 += __shfl_xor(p2, 32); p3 += __shfl_xor(p3, 32);
  if (l < 32) {
    aggl[w * 128 +  0 + l] = p0;
    aggl[w * 128 + 32 + l] = p1;
    aggl[w * 128 + 64 + l] = p2;
    aggl[w * 128 + 96 + l] = p3;
  }
  __syncthreads();
  if (tid < 128) {
    float vf = aggl[tid] + aggl[128 + tid] + aggl[256 + tid] + aggl[384 + tid] + sav;
    vfb[(size_t)bi * 128 + tid] = vf;
    atomicMax(&poolU[b * 128 + tid], fkey(vf));   // device-scope, XCD-coherent
  }
}

// ---------- out MLP: v_out = silu([vf|pool] @ W_out + b), split-K, 2 rows ----------
__global__ __launch_bounds__(256) void k_out(
    const float* __restrict__ vfb, const unsigned* __restrict__ poolU,
    const float* __restrict__ W, const float* __restrict__ bias,
    float* __restrict__ vout) {
  __shared__ float x[2][256];
  __shared__ float par[2][2][128];
  const int r0 = blockIdx.x * 2;
  const int b  = r0 >> 7;
  const int t  = threadIdx.x;
  const int c  = t & 127;
  const int hf = t >> 7;
  #pragma unroll
  for (int rr = 0; rr < 2; ++rr)
    x[rr][t] = (t < 128) ? vfb[(r0 + rr) * 128 + t]
                         : funkey(poolU[b * 128 + (t - 128)]);
  __syncthreads();
  {
    float a0 = 0.f, a1 = 0.f;
    const int k0 = hf * 128;
    for (int k4 = k0; k4 < k0 + 128; k4 += 4) {
      f4v x0 = *(const f4v*)&x[0][k4];
      f4v x1 = *(const f4v*)&x[1][k4];
      #pragma unroll
      for (int u = 0; u < 4; ++u) {
        float wv = W[(k4 + u) * 128 + c];
        a0 += x0[u] * wv; a1 += x1[u] * wv;
      }
    }
    par[hf][0][c] = a0; par[hf][1][c] = a1;
  }
  __syncthreads();
  if (hf == 0) {
    const float bvv = bias[c];
    #pragma unroll
    for (int rr = 0; rr < 2; ++rr)
      vout[(r0 + rr) * 128 + c] = silu_f(par[0][rr][c] + par[1][rr][c] + bvv);
  }
}

extern "C" void kernel_launch(void* const* d_in, const int* in_sizes, int n_in,
                              void* d_out, int out_size, void* d_ws, size_t ws_size,
                              hipStream_t stream) {
  const float* v_f    = (const float*)d_in[0];
  const float* e_f    = (const float*)d_in[1];
  const float* p_pe   = (const float*)d_in[2];
  const float* t_pe   = (const float*)d_in[3];
  const float* W_vpe  = (const float*)d_in[4];
  const float* b_vpe  = (const float*)d_in[5];
  const float* W_epe  = (const float*)d_in[6];
  const float* b_epe  = (const float*)d_in[7];
  const float* W_ev1  = (const float*)d_in[8];
  const float* b_ev1  = (const float*)d_in[9];
  const float* W_ev2  = (const float*)d_in[10];
  const float* b_ev2  = (const float*)d_in[11];
  const float* W_q    = (const float*)d_in[12];
  const float* b_q    = (const float*)d_in[13];
  const float* W_k    = (const float*)d_in[14];
  const float* b_k    = (const float*)d_in[15];
  const float* W_self = (const float*)d_in[16];
  const float* b_self = (const float*)d_in[17];
  const float* W_out  = (const float*)d_in[18];
  const float* b_out  = (const float*)d_in[19];

  char* ws = (char*)d_ws;
  unsigned short* vb16  = (unsigned short*)(ws + 0);        // 262144
  float*          qbuf  = (float*)(ws + 262144);            // 524288
  float*          kbuf  = (float*)(ws + 786432);            // 524288
  float*          sabuf = (float*)(ws + 1310720);           // 524288
  float*          vfbuf = (float*)(ws + 1835008);           // 524288
  float*          evic  = (float*)(ws + 2359296);           // 524288
  unsigned*       poolU = (unsigned*)(ws + 2883584);        // 4096
  float*          tc    = (float*)(ws + 2887680);           // 4096
  short*          wf1   = (short*)(ws + 2891776);           // 32768
  short*          wf2   = (short*)(ws + 2924544);           // 65536
  short*          wf3   = (short*)(ws + 2990080);           // 32768
  float*          atten = (float*)(ws + 3022848);           // 8388608 -> 11.4MB

  float* v_out = (float*)d_out;
  float* out_e = (float*)d_out + 131072;

  k_front<<<773, 256, 0, stream>>>(W_epe, wf1, W_ev1, wf2, W_ev2, wf3,
                                   t_pe, b_epe, tc, poolU,
                                   v_f, p_pe, W_vpe, b_vpe, W_q, b_q,
                                   W_k, b_k, W_self, b_self, W_ev1, b_ev1,
                                   vb16, qbuf, kbuf, sabuf, evic);
  k_atten<<<512, 256, 0, stream>>>(qbuf, kbuf, atten);
  k_edge<<<1024, 256, 0, stream>>>(e_f, vb16, wf1, wf2, wf3, tc, evic,
                                   b_ev2, atten, sabuf, out_e, vfbuf, poolU);
  k_out<<<512, 256, 0, stream>>>(vfbuf, poolU, W_out, b_out, v_out);
}